// Round 1
// baseline (477.300 us; speedup 1.0000x reference)
//
#include <hip/hip_runtime.h>
#include <math.h>

#define BATCH 32
#define HIN   224
#define WIN   224
#define CIN   3
#define KOUT  64
#define RK    5
#define HOUT  220
#define WOUT  220

#define TILE_H 20
#define TILE_W 10
#define PATCH_H (TILE_H + RK - 1)   // 24
#define PATCH_W (TILE_W + RK - 1)   // 14
#define PATCH_WP 16                 // padded LDS row stride (16B-aligned rows -> b128 reads)
#define ROWS_PER_WAVE 5

#define NTOT ((size_t)BATCH * HOUT * WOUT * KOUT)   // 99,123,200 per output tensor

__device__ __forceinline__ float softplus_f(float x) {
    // stable: max(x,0) + log1p(exp(-|x|))  == jax.nn.softplus
    return fmaxf(x, 0.0f) + log1pf(expf(-fabsf(x)));
}

__global__ __launch_bounds__(256, 4) void vdp_conv_kernel(
    const float* __restrict__ mu_in,
    const float* __restrict__ w_mu,
    const float* __restrict__ w_sigma,
    float* __restrict__ out)
{
    __shared__ float lds_in[CIN][PATCH_H][PATCH_WP];  // planar input patch
    __shared__ float lds_ssq[PATCH_H][PATCH_WP];      // sum over c of x^2
    __shared__ float lds_sq[TILE_H][TILE_W];          // per-pixel window mean of x^2

    const int tid  = threadIdx.x;
    const int lane = tid & 63;       // = output channel k
    const int wid  = tid >> 6;       // wave id 0..3

    const int b   = blockIdx.z;
    const int ho0 = blockIdx.y * TILE_H;
    const int wo0 = blockIdx.x * TILE_W;

    // ---- stage input patch (global -> LDS, planar) + channel-squared plane ----
    for (int idx = tid; idx < PATCH_H * PATCH_W; idx += 256) {
        const int row = idx / PATCH_W;
        const int col = idx - row * PATCH_W;
        const float* s = mu_in + (((size_t)b * HIN + (ho0 + row)) * WIN + (wo0 + col)) * CIN;
        const float x0 = s[0], x1 = s[1], x2 = s[2];
        lds_in[0][row][col] = x0;
        lds_in[1][row][col] = x1;
        lds_in[2][row][col] = x2;
        lds_ssq[row][col]   = x0 * x0 + x1 * x1 + x2 * x2;
    }

    const float wsig2 = softplus_f(w_sigma[lane]);   // softplus(w_sigma[k])

    __syncthreads();

    // ---- per-pixel 5x5 window mean of squares (one thread per tile pixel) ----
    if (tid < TILE_H * TILE_W) {
        const int pr = tid / TILE_W;
        const int pc = tid - pr * TILE_W;
        float ssum = 0.0f;
        #pragma unroll
        for (int kh = 0; kh < RK; ++kh)
            #pragma unroll
            for (int kw = 0; kw < RK; ++kw)
                ssum += lds_ssq[pr + kh][pc + kw];
        lds_sq[pr][pc] = ssum * (1.0f / 75.0f);
    }
    __syncthreads();

    // ---- conv: wave owns rows [wid*5, wid*5+5) x 10 wo, fixed k = lane ----
    float acc[ROWS_PER_WAVE][TILE_W];
    #pragma unroll
    for (int o = 0; o < ROWS_PER_WAVE; ++o)
        #pragma unroll
        for (int j = 0; j < TILE_W; ++j) acc[o][j] = 0.0f;

    const int r0 = wid * ROWS_PER_WAVE;

    #pragma unroll
    for (int c = 0; c < CIN; ++c) {
        // 25 weights for this channel, k = lane (register cached; L1-hot reloads)
        float wv[RK * RK];
        #pragma unroll
        for (int t = 0; t < RK * RK; ++t)
            wv[t] = w_mu[(t * CIN + c) * KOUT + lane];

        #pragma unroll
        for (int rr = 0; rr < ROWS_PER_WAVE + RK - 1; ++rr) {   // 9 patch rows per wave
            float v[PATCH_W];
            #pragma unroll
            for (int j = 0; j < PATCH_W; ++j)
                v[j] = lds_in[c][r0 + rr][j];   // wave-uniform addr -> broadcast reads
            #pragma unroll
            for (int kh = 0; kh < RK; ++kh) {
                const int oo = rr - kh;
                if (oo >= 0 && oo < ROWS_PER_WAVE) {   // folds at compile time
                    #pragma unroll
                    for (int kw = 0; kw < RK; ++kw) {
                        const float w = wv[kh * RK + kw];
                        #pragma unroll
                        for (int j = 0; j < TILE_W; ++j)
                            acc[oo][j] = fmaf(v[j + kw], w, acc[oo][j]);
                    }
                }
            }
        }
    }

    // ---- epilogue: coalesced 256B wave-stores (lane = k fastest dim) ----
    float* __restrict__ mu_o  = out;
    float* __restrict__ sig_o = out + NTOT;
    #pragma unroll
    for (int oo = 0; oo < ROWS_PER_WAVE; ++oo) {
        const int ho = ho0 + r0 + oo;
        const size_t base = (((size_t)b * HOUT + ho) * WOUT + wo0) * KOUT + lane;
        #pragma unroll
        for (int j = 0; j < TILE_W; ++j) {
            mu_o[base + (size_t)j * KOUT] = acc[oo][j];
            const float sq = lds_sq[r0 + oo][j];
            sig_o[base + (size_t)j * KOUT] = softplus_f(wsig2 * sq);
        }
    }
}

__global__ __launch_bounds__(256) void vdp_kl_kernel(
    const float* __restrict__ w_mu,
    const float* __restrict__ w_sigma,
    float* __restrict__ out)
{
    __shared__ float red[4];
    const int tid = threadIdx.x;

    float s = 0.0f;
    for (int i = tid; i < RK * RK * CIN * KOUT; i += 256) {
        const float v = w_mu[i];
        s = fmaf(v, v, s);
    }
    // kl = 0.5*( log(0.01) - 1 + (1/64)*sum_k(-ws + softplus(ws)*100) + sum(mu^2)*100/4800 )
    float u = s * (100.0f / 4800.0f);
    if (tid < KOUT) {
        const float ws = w_sigma[tid];
        u += (-ws + softplus_f(ws) * 100.0f) * (1.0f / 64.0f);
    }
    #pragma unroll
    for (int off = 32; off > 0; off >>= 1)
        u += __shfl_down(u, off, 64);
    if ((tid & 63) == 0) red[tid >> 6] = u;
    __syncthreads();
    if (tid == 0) {
        const float U = red[0] + red[1] + red[2] + red[3];
        out[2 * NTOT] = 0.5f * (-4.6051701860f - 1.0f + U);
    }
}

extern "C" void kernel_launch(void* const* d_in, const int* in_sizes, int n_in,
                              void* d_out, int out_size, void* d_ws, size_t ws_size,
                              hipStream_t stream)
{
    (void)in_sizes; (void)n_in; (void)d_ws; (void)ws_size; (void)out_size;
    const float* mu_in   = (const float*)d_in[0];
    const float* w_mu    = (const float*)d_in[1];
    const float* w_sigma = (const float*)d_in[2];
    float* out = (float*)d_out;

    dim3 grid(WOUT / TILE_W, HOUT / TILE_H, BATCH);   // (22, 11, 32) = 7744 blocks
    vdp_conv_kernel<<<grid, 256, 0, stream>>>(mu_in, w_mu, w_sigma, out);
    vdp_kl_kernel<<<1, 256, 0, stream>>>(w_mu, w_sigma, out);
}

// Round 3
// 227.100 us; speedup vs baseline: 2.1017x; 2.1017x over previous
//
#include <hip/hip_runtime.h>
#include <math.h>

#define BATCH 32
#define HIN   224
#define WIN   224
#define CIN   3
#define KOUT  64
#define RK    5
#define HOUT  220
#define WOUT  220

#define TS      16                  // output tile: 16x16 pixels
#define PATCH   (TS + RK - 1)       // 20
#define PWP     24                  // padded LDS row stride (96B rows -> b128-friendly, conflict-free)
#define NTOT ((size_t)BATCH * HOUT * WOUT * KOUT)

typedef float v4f __attribute__((ext_vector_type(4)));  // native vector: OK for nontemporal builtins

// --- HW transcendentals: v_exp_f32 = 2^x, v_log_f32 = log2(x) ---
__device__ __forceinline__ float exp2_hw(float x) { float r; asm("v_exp_f32 %0, %1" : "=v"(r) : "v"(x)); return r; }
__device__ __forceinline__ float log2_hw(float x) { float r; asm("v_log_f32 %0, %1" : "=v"(r) : "v"(x)); return r; }

#define LOG2E 1.44269504088896f
#define LN2   0.69314718055995f

// general stable softplus (abs-error ~1e-6, threshold is 0.127 absolute)
__device__ __forceinline__ float softplus_hw(float x) {
    float t = exp2_hw(-fabsf(x) * LOG2E);
    return fmaxf(x, 0.0f) + LN2 * log2_hw(1.0f + t);
}
// softplus for y >= 0 (Sigma path: y = softplus(ws)*sq >= 0)
__device__ __forceinline__ float softplus_pos(float y) {
    return y + LN2 * log2_hw(1.0f + exp2_hw(-y * LOG2E));
}

__global__ __launch_bounds__(256, 2) void vdp_conv_kernel(
    const float* __restrict__ mu_in,
    const float* __restrict__ w_mu,
    const float* __restrict__ w_sigma,
    float* __restrict__ out)
{
    __shared__ float s_in[CIN * PATCH * PWP];    // planar input patch  (5760 B)
    __shared__ float s_ssq[PATCH * PWP];         // sum_c x^2           (1920 B)
    __shared__ float s_sq[TS * TS];              // 5x5 window mean     (1024 B)
    __shared__ float s_w[RK * RK * CIN * KOUT];  // weights [c*25+kh*5+kw][k] (19200 B)

    const int tid  = threadIdx.x;
    const int lane = tid & 63;
    const int wid  = tid >> 6;
    const int kg   = lane & 15;               // k-group: owns k = 4*kg .. 4*kg+3
    const int rt   = (wid << 2) | (lane >> 4); // owned output row in tile, 0..15

    const int b = blockIdx.z;
    int ho0 = blockIdx.y * TS; if (ho0 > HOUT - TS) ho0 = HOUT - TS;  // clamp: overlap recompute (bit-identical)
    int wo0 = blockIdx.x * TS; if (wo0 > WOUT - TS) wo0 = WOUT - TS;

    // ---- stage weights: w_mu[(kh*5+kw)*3+c][k] -> s_w[(c*25+kh*5+kw)][k] ----
    for (int i = tid; i < RK * RK * CIN * KOUT; i += 256) {
        const int k = i & 63;
        const int t = i >> 6;               // (kh*5+kw)*3 + c
        const int khkw = t / 3;
        const int c = t - khkw * 3;
        s_w[(c * 25 + khkw) * KOUT + k] = w_mu[i];
    }
    // ---- stage input patch (planar) + channel-summed squares ----
    for (int idx = tid; idx < PATCH * PATCH; idx += 256) {
        const int row = idx / PATCH;
        const int col = idx - row * PATCH;
        const float* s = mu_in + (((size_t)b * HIN + (ho0 + row)) * WIN + (wo0 + col)) * CIN;
        const float x0 = s[0], x1 = s[1], x2 = s[2];
        s_in[(0 * PATCH + row) * PWP + col] = x0;
        s_in[(1 * PATCH + row) * PWP + col] = x1;
        s_in[(2 * PATCH + row) * PWP + col] = x2;
        s_ssq[row * PWP + col] = fmaf(x0, x0, fmaf(x1, x1, x2 * x2));
    }
    __syncthreads();

    // ---- per-pixel 5x5 box mean of squares (1 thread per tile pixel) ----
    {
        const int pr = tid >> 4, pc = tid & 15;
        float ssum = 0.0f;
        #pragma unroll
        for (int kh = 0; kh < RK; ++kh)
            #pragma unroll
            for (int kw = 0; kw < RK; ++kw)
                ssum += s_ssq[(pr + kh) * PWP + (pc + kw)];
        s_sq[(pr << 4) | pc] = ssum * (1.0f / 75.0f);
    }
    __syncthreads();

    // ---- conv: lane owns 1 output row (rt) x 16 cols x 4 k-channels ----
    float acc[TS][4];
    #pragma unroll
    for (int j = 0; j < TS; ++j) { acc[j][0] = acc[j][1] = acc[j][2] = acc[j][3] = 0.0f; }

    #pragma unroll 1
    for (int t = 0; t < CIN * RK; ++t) {        // t = c*5 + kh
        const int c  = t / 5;
        const int kh = t - c * 5;
        const float* rp = s_in + (c * PATCH + rt + kh) * PWP;   // 16B-aligned (96B row stride)
        const v4f q0 = *(const v4f*)(rp + 0);
        const v4f q1 = *(const v4f*)(rp + 4);
        const v4f q2 = *(const v4f*)(rp + 8);
        const v4f q3 = *(const v4f*)(rp + 12);
        const v4f q4 = *(const v4f*)(rp + 16);
        float v[PATCH];
        v[0]=q0.x; v[1]=q0.y; v[2]=q0.z; v[3]=q0.w;
        v[4]=q1.x; v[5]=q1.y; v[6]=q1.z; v[7]=q1.w;
        v[8]=q2.x; v[9]=q2.y; v[10]=q2.z; v[11]=q2.w;
        v[12]=q3.x; v[13]=q3.y; v[14]=q3.z; v[15]=q3.w;
        v[16]=q4.x; v[17]=q4.y; v[18]=q4.z; v[19]=q4.w;

        const float* wp = s_w + (c * 25 + kh * 5) * KOUT + (kg << 2);
        #pragma unroll
        for (int kw = 0; kw < RK; ++kw) {
            const v4f w4 = *(const v4f*)(wp + kw * KOUT);  // broadcast b128, 2-way max
            #pragma unroll
            for (int j = 0; j < TS; ++j) {
                const float x = v[j + kw];
                acc[j][0] = fmaf(x, w4.x, acc[j][0]);
                acc[j][1] = fmaf(x, w4.y, acc[j][1]);
                acc[j][2] = fmaf(x, w4.z, acc[j][2]);
                acc[j][3] = fmaf(x, w4.w, acc[j][3]);
            }
        }
    }

    // ---- epilogue: dwordx4 nontemporal stores (full-line, two streams) ----
    const v4f ws4 = *(const v4f*)(w_sigma + (kg << 2));
    v4f wsg;
    wsg.x = softplus_hw(ws4.x); wsg.y = softplus_hw(ws4.y);
    wsg.z = softplus_hw(ws4.z); wsg.w = softplus_hw(ws4.w);

    const size_t prow = ((size_t)b * HOUT + (ho0 + rt)) * WOUT + wo0;
    float* mu_p = out + prow * KOUT + (kg << 2);
    float* sg_p = mu_p + NTOT;

    #pragma unroll
    for (int j = 0; j < TS; ++j) {
        v4f m;
        m.x = acc[j][0]; m.y = acc[j][1]; m.z = acc[j][2]; m.w = acc[j][3];
        __builtin_nontemporal_store(m, (v4f*)(mu_p + (size_t)j * KOUT));
        const float sq = s_sq[(rt << 4) | j];
        v4f sg;
        sg.x = softplus_pos(wsg.x * sq); sg.y = softplus_pos(wsg.y * sq);
        sg.z = softplus_pos(wsg.z * sq); sg.w = softplus_pos(wsg.w * sq);
        __builtin_nontemporal_store(sg, (v4f*)(sg_p + (size_t)j * KOUT));
    }
}

__global__ __launch_bounds__(256) void vdp_kl_kernel(
    const float* __restrict__ w_mu,
    const float* __restrict__ w_sigma,
    float* __restrict__ out)
{
    __shared__ float red[4];
    const int tid = threadIdx.x;

    float s = 0.0f;
    for (int i = tid; i < RK * RK * CIN * KOUT; i += 256) {
        const float v = w_mu[i];
        s = fmaf(v, v, s);
    }
    // kl = 0.5*( log(0.01) - 1 + (1/64)*sum_k(-ws + softplus(ws)*100) + sum(mu^2)*100/4800 )
    float u = s * (100.0f / 4800.0f);
    if (tid < KOUT) {
        const float ws = w_sigma[tid];
        u += (-ws + softplus_hw(ws) * 100.0f) * (1.0f / 64.0f);
    }
    #pragma unroll
    for (int off = 32; off > 0; off >>= 1)
        u += __shfl_down(u, off, 64);
    if ((tid & 63) == 0) red[tid >> 6] = u;
    __syncthreads();
    if (tid == 0) {
        const float U = red[0] + red[1] + red[2] + red[3];
        out[2 * NTOT] = 0.5f * (-4.6051701860f - 1.0f + U);
    }
}

extern "C" void kernel_launch(void* const* d_in, const int* in_sizes, int n_in,
                              void* d_out, int out_size, void* d_ws, size_t ws_size,
                              hipStream_t stream)
{
    (void)in_sizes; (void)n_in; (void)d_ws; (void)ws_size; (void)out_size;
    const float* mu_in   = (const float*)d_in[0];
    const float* w_mu    = (const float*)d_in[1];
    const float* w_sigma = (const float*)d_in[2];
    float* out = (float*)d_out;

    dim3 grid((WOUT + TS - 1) / TS, (HOUT + TS - 1) / TS, BATCH);  // 14 x 14 x 32 = 6272 blocks
    vdp_conv_kernel<<<grid, 256, 0, stream>>>(mu_in, w_mu, w_sigma, out);
    vdp_kl_kernel<<<1, 256, 0, stream>>>(w_mu, w_sigma, out);
}